// Round 17
// baseline (83.262 us; speedup 1.0000x reference)
//
#include <hip/hip_runtime.h>

#define BN 8192
#define BD 256
#define NTRIALS 150
#define HALF 75

typedef unsigned int uint2v __attribute__((ext_vector_type(2)));

// Butterfly reduce — identical tree/pairings/operand-order to the proven
// `for m in {32,16,8,4,2,1}: v += __shfl_xor(v,m,64)`:
//   m=32: __builtin_amdgcn_permlane32_swap (VALU; HW-verified primitive for
//         lane[i]<->lane[i+32], m255). With both inputs = v:
//         r.x={v.lo,v.lo}, r.y={v.hi,v.hi} -> r.x+r.y = v[l]+v[l^32]
//         (upper half commuted; fp add commutative -> bitwise identical).
//   m=16/8/4: ds_swizzle BitMode xor masks (proven R12/R14/R15/R16)
//   m=2/1: DPP quad_perm (proven R12/R14/R15/R16)
__device__ __forceinline__ float wave_reduce_sum(float v) {
    uint2v r = __builtin_amdgcn_permlane32_swap(__float_as_uint(v), __float_as_uint(v),
                                                false, false);                   // lane ^ 32
    v = __uint_as_float(r.x) + __uint_as_float(r.y);
    v += __int_as_float(__builtin_amdgcn_ds_swizzle(__float_as_int(v), 0x401F)); // lane ^ 16
    v += __int_as_float(__builtin_amdgcn_ds_swizzle(__float_as_int(v), 0x201F)); // lane ^ 8
    v += __int_as_float(__builtin_amdgcn_ds_swizzle(__float_as_int(v), 0x101F)); // lane ^ 4
    v += __int_as_float(__builtin_amdgcn_mov_dpp(__float_as_int(v), 0x4E, 0xF, 0xF, false)); // ^2
    v += __int_as_float(__builtin_amdgcn_mov_dpp(__float_as_int(v), 0xB1, 0xF, 0xF, false)); // ^1
    return v;
}

// Kernel 1: count genuine (tgt == 0). Single block. (verbatim; int reduce exact)
__global__ __launch_bounds__(1024) void count_genuine_kernel(
    const int* __restrict__ tgt, int* __restrict__ cnt)
{
    __shared__ int lds[16];
    const int t = threadIdx.x;
    int c = 0;
    for (int i = t; i < BN; i += 1024) c += (tgt[i] == 0) ? 1 : 0;
    #pragma unroll
    for (int m = 32; m > 0; m >>= 1) c += __shfl_xor(c, m, 64);
    if ((t & 63) == 0) lds[t >> 6] = c;
    __syncthreads();
    if (t == 0) {
        int s = 0;
        #pragma unroll
        for (int w = 0; w < 16; ++w) s += lds[w];
        *cnt = s;
    }
}

// Kernel 2: sq[i] = sum_d hd[i][d]^2. One wave per row. (same reduce tree)
__global__ __launch_bounds__(256) void sqnorm_kernel(
    const float* __restrict__ hd, float* __restrict__ sq)
{
    const int lane = threadIdx.x & 63;
    const int row  = blockIdx.x * 4 + (threadIdx.x >> 6);
    const float4 a = *reinterpret_cast<const float4*>(hd + row * BD + lane * 4);
    float s = a.x * a.x + a.y * a.y + a.z * a.z + a.w * a.w;
    s = wave_reduce_sum(s);
    if (lane == 0) sq[row] = s;
}

// Compute one trial's dn — BYTE-IDENTICAL text to passing R14.
#define TRIAL_COMPUTE_PF(CSLOT, BJSLOT, SQSLOT, PFT, CSAVE, DNSAVE)             \
    {                                                                           \
        const int    c_  = CSLOT;                                               \
        const float4 bj  = BJSLOT;                                              \
        const float  sqc = SQSLOT;                                              \
        {                                                                       \
            int c2 = (int)(unrow[PFT] * lnf);                                   \
            c2 = min(c2, lnm1);                                                 \
            c2 = __builtin_amdgcn_readfirstlane(c2);                            \
            CSLOT  = c2;                                                        \
            BJSLOT = *reinterpret_cast<const float4*>(hd + c2 * BD + lane * 4); \
            SQSLOT = sq[c2];                                                    \
        }                                                                       \
        float p = a.x * bj.x + a.y * bj.y + a.z * bj.z + a.w * bj.w;            \
        const float dn = (sqi - 2.0f * wave_reduce_sum(p)) + sqc;               \
        CSAVE  = c_;                                                            \
        DNSAVE = dn;                                                            \
    }

// Same compute text, no prefetch (final peeled group). (verbatim from R14)
#define TRIAL_COMPUTE_NP(CSLOT, BJSLOT, SQSLOT, CSAVE, DNSAVE)                  \
    {                                                                           \
        const int    c_  = CSLOT;                                               \
        const float4 bj  = BJSLOT;                                              \
        const float  sqc = SQSLOT;                                              \
        float p = a.x * bj.x + a.y * bj.y + a.z * bj.z + a.w * bj.w;            \
        const float dn = (sqi - 2.0f * wave_reduce_sum(p)) + sqc;               \
        CSAVE  = c_;                                                            \
        DNSAVE = dn;                                                            \
    }

// In-order break / strict-< argmin — BYTE-IDENTICAL text to passing R8/R11/R12/R14.
#define TRIAL_CHECK(CSAVE, DNSAVE)                                              \
    {                                                                           \
        const float z = dst_pos - (DNSAVE);                                     \
        if ((z < 0.0f) && (z + margin > 0.0f)) { chosen = (CSAVE); goto done; } \
        if ((DNSAVE) < best) { best = (DNSAVE); best_c = (CSAVE); }             \
    }

#define PROLOGUE_SLOT(CS, BJS, SQS, T)                                          \
    {                                                                           \
        int c = (int)(unrow[T] * lnf);                                          \
        c = min(c, lnm1);                                                       \
        c = __builtin_amdgcn_readfirstlane(c);                                  \
        CS  = c;                                                                \
        BJS = *reinterpret_cast<const float4*>(hd + c * BD + lane * 4);         \
        SQS = sq[c];                                                            \
    }

// Kernel 3: TWO waves per anchor — wave A scans trials 0..74, wave B 75..149.
// (verbatim structure from passing R14)
__global__ __launch_bounds__(256) void triplet_kernel(
    const float* __restrict__ hd, const int* __restrict__ tgt,
    const float* __restrict__ margin_p, const float* __restrict__ u_pos,
    const float* __restrict__ u_neg, const float* __restrict__ sq,
    const int* __restrict__ cnt, float* __restrict__ out)
{
    __shared__ int   s_chosen[2][2];
    __shared__ float s_best[2][2];
    __shared__ int   s_bestc[2][2];
    __shared__ int   s_aflag[2];

    const int lane = threadIdx.x & 63;
    const int w    = threadIdx.x >> 6;
    const int ancl = w >> 1;     // local anchor 0/1
    const int half = w & 1;      // 0: trials 0-74, 1: trials 75-149
    const int i    = blockIdx.x * 2 + ancl;

    if (threadIdx.x < 2) s_aflag[threadIdx.x] = 0;
    __syncthreads();

    // anchor row in registers (float4 per lane: 64*4 = 256 = D)
    const float4 a = *reinterpret_cast<const float4*>(hd + i * BD + lane * 4);
    const float sqi = sq[i];

    const int ng = *cnt;
    const int ti = tgt[i];
    const int len_pos = (ti == 0) ? ng : (BN - ng);
    const int len_neg = (ti == 0) ? (BN - ng) : ng;

    // positive index — exact integer/fp32 replication of the reference
    const bool excl = (i < len_pos);
    const int  eff  = len_pos - (excl ? 1 : 0);
    const float up  = u_pos[i];
    int u = (int)(up * (float)eff);        // fp32 multiply, trunc toward zero
    u = min(u, eff - 1);
    const int pos_idx = u + ((excl && (u >= i)) ? 1 : 0);

    // dst_pos = (sq_i - 2*dot) + sq_j  (same expression/order as all passing rounds;
    // computed redundantly in both halves -> identical bits -> consistent decisions)
    const float4 bp = *reinterpret_cast<const float4*>(hd + pos_idx * BD + lane * 4);
    float pp = a.x * bp.x + a.y * bp.y + a.z * bp.z + a.w * bp.w;
    const float dot_pos = wave_reduce_sum(pp);
    const float dst_pos = (sqi - 2.0f * dot_pos) + sq[pos_idx];

    float* orow = out + i * (3 * BD);
    if (half == 0) {   // anchor + positive rows; overlaps with the scan
        *reinterpret_cast<float4*>(orow + lane * 4) = a;
        *reinterpret_cast<float4*>(orow + BD + lane * 4) = bp;
    }

    const float margin = margin_p[0];
    const float lnf    = (float)len_neg;
    const int   lnm1   = len_neg - 1;

    int   chosen = -1;
    float best   = __builtin_inff();
    int   best_c = 0;
    const float* unrow = u_neg + i * NTRIALS + half * HALF;

    {
        // prologue: prefetch local trials 0,1,2 into slots A,B,C
        int cA, cB, cC; float4 bjA, bjB, bjC; float sqA, sqB, sqC;
        PROLOGUE_SLOT(cA, bjA, sqA, 0)
        PROLOGUE_SLOT(cB, bjB, sqB, 1)
        PROLOGUE_SLOT(cC, bjC, sqC, 2)

        // main loop: t = 0,3,...,69 — computes local trials t..t+2, prefetches t+3..t+5
        for (int t = 0; t < HALF - 3; t += 3) {
            int cs0, cs1, cs2;
            float dn0, dn1, dn2;
            TRIAL_COMPUTE_PF(cA, bjA, sqA, t + 3, cs0, dn0)
            TRIAL_COMPUTE_PF(cB, bjB, sqB, t + 4, cs1, dn1)
            TRIAL_COMPUTE_PF(cC, bjC, sqC, t + 5, cs2, dn2)
            TRIAL_CHECK(cs0, dn0)
            TRIAL_CHECK(cs1, dn1)
            TRIAL_CHECK(cs2, dn2)
            // B only: bail if A already hit (B's results are then discarded anyway)
            if (half && *(volatile int*)&s_aflag[ancl]) goto bail;
        }
        // peeled final group: local trials 72,73,74 — no prefetch
        {
            int cs0, cs1, cs2;
            float dn0, dn1, dn2;
            TRIAL_COMPUTE_NP(cA, bjA, sqA, cs0, dn0)
            TRIAL_COMPUTE_NP(cB, bjB, sqB, cs1, dn1)
            TRIAL_COMPUTE_NP(cC, bjC, sqC, cs2, dn2)
            TRIAL_CHECK(cs0, dn0)
            TRIAL_CHECK(cs1, dn1)
            TRIAL_CHECK(cs2, dn2)
        }
    }
done:
    if (half == 0 && chosen >= 0 && lane == 0) *(volatile int*)&s_aflag[ancl] = 1;
bail:
    if (lane == 0) {
        s_chosen[ancl][half] = chosen;
        s_best[ancl][half]   = best;
        s_bestc[ancl][half]  = best_c;
    }
    __syncthreads();

    if (half == 0) {
        const int chA = s_chosen[ancl][0];
        const int chB = s_chosen[ancl][1];
        int neg;
        if (chA >= 0) {
            neg = chA;                               // earliest hit: half A wins
        } else if (chB >= 0) {
            neg = chB;                               // hit only in half B
        } else {
            const float bA = s_best[ancl][0];
            const float bB = s_best[ancl][1];
            neg = (bB < bA) ? s_bestc[ancl][1]       // strict <: tie -> A (first occ.)
                            : s_bestc[ancl][0];
        }
        const float4 bn = *reinterpret_cast<const float4*>(hd + neg * BD + lane * 4);
        *reinterpret_cast<float4*>(orow + 2 * BD + lane * 4) = bn;
    }
}

extern "C" void kernel_launch(void* const* d_in, const int* in_sizes, int n_in,
                              void* d_out, int out_size, void* d_ws, size_t ws_size,
                              hipStream_t stream) {
    const float* hd     = (const float*)d_in[0];
    const int*   tgt    = (const int*)d_in[1];
    const float* margin = (const float*)d_in[2];
    const float* u_pos  = (const float*)d_in[3];
    const float* u_neg  = (const float*)d_in[4];
    float* out = (float*)d_out;

    float* sq  = (float*)d_ws;
    int*   cnt = (int*)((char*)d_ws + BN * sizeof(float));

    count_genuine_kernel<<<1, 1024, 0, stream>>>(tgt, cnt);
    sqnorm_kernel<<<BN / 4, 256, 0, stream>>>(hd, sq);
    triplet_kernel<<<BN / 2, 256, 0, stream>>>(hd, tgt, margin, u_pos, u_neg, sq, cnt, out);
}

// Round 18
// 76.561 us; speedup vs baseline: 1.0875x; 1.0875x over previous
//
#include <hip/hip_runtime.h>

#define BN 8192
#define BD 256
#define NTRIALS 150
#define HALF 75

// EXACT R12/R14 reduce (best passing config): shfl^32 + swizzle^16/^8/^4 + DPP^2/^1.
__device__ __forceinline__ float wave_reduce_sum(float v) {
    v += __shfl_xor(v, 32, 64);                                                  // lane ^ 32
    v += __int_as_float(__builtin_amdgcn_ds_swizzle(__float_as_int(v), 0x401F)); // lane ^ 16
    v += __int_as_float(__builtin_amdgcn_ds_swizzle(__float_as_int(v), 0x201F)); // lane ^ 8
    v += __int_as_float(__builtin_amdgcn_ds_swizzle(__float_as_int(v), 0x101F)); // lane ^ 4
    v += __int_as_float(__builtin_amdgcn_mov_dpp(__float_as_int(v), 0x4E, 0xF, 0xF, false)); // ^2
    v += __int_as_float(__builtin_amdgcn_mov_dpp(__float_as_int(v), 0xB1, 0xF, 0xF, false)); // ^1
    return v;
}

// Kernel 1: count genuine (tgt == 0). Single block. (verbatim)
__global__ __launch_bounds__(1024) void count_genuine_kernel(
    const int* __restrict__ tgt, int* __restrict__ cnt)
{
    __shared__ int lds[16];
    const int t = threadIdx.x;
    int c = 0;
    for (int i = t; i < BN; i += 1024) c += (tgt[i] == 0) ? 1 : 0;
    #pragma unroll
    for (int m = 32; m > 0; m >>= 1) c += __shfl_xor(c, m, 64);
    if ((t & 63) == 0) lds[t >> 6] = c;
    __syncthreads();
    if (t == 0) {
        int s = 0;
        #pragma unroll
        for (int w = 0; w < 16; ++w) s += lds[w];
        *cnt = s;
    }
}

// Kernel 2: sq[i] = sum_d hd[i][d]^2. One wave per row. (verbatim from R12/R14)
__global__ __launch_bounds__(256) void sqnorm_kernel(
    const float* __restrict__ hd, float* __restrict__ sq)
{
    const int lane = threadIdx.x & 63;
    const int row  = blockIdx.x * 4 + (threadIdx.x >> 6);
    const float4 a = *reinterpret_cast<const float4*>(hd + row * BD + lane * 4);
    float s = a.x * a.x + a.y * a.y + a.z * a.z + a.w * a.w;
    s = wave_reduce_sum(s);
    if (lane == 0) sq[row] = s;
}

// Compute one trial's dn — R14 text (readfirstlane scalarization of the
// wave-uniform candidate index: bit-exact identity, scalarizes sq[] load and
// row-gather base).
#define TRIAL_COMPUTE_PF(CSLOT, BJSLOT, SQSLOT, PFT, CSAVE, DNSAVE)             \
    {                                                                           \
        const int    c_  = CSLOT;                                               \
        const float4 bj  = BJSLOT;                                              \
        const float  sqc = SQSLOT;                                              \
        {                                                                       \
            int c2 = (int)(unrow[PFT] * lnf);                                   \
            c2 = min(c2, lnm1);                                                 \
            c2 = __builtin_amdgcn_readfirstlane(c2);                            \
            CSLOT  = c2;                                                        \
            BJSLOT = *reinterpret_cast<const float4*>(hd + c2 * BD + lane * 4); \
            SQSLOT = sq[c2];                                                    \
        }                                                                       \
        float p = a.x * bj.x + a.y * bj.y + a.z * bj.z + a.w * bj.w;            \
        const float dn = (sqi - 2.0f * wave_reduce_sum(p)) + sqc;               \
        CSAVE  = c_;                                                            \
        DNSAVE = dn;                                                            \
    }

// Same compute text, no prefetch (final peeled group). (verbatim from R14)
#define TRIAL_COMPUTE_NP(CSLOT, BJSLOT, SQSLOT, CSAVE, DNSAVE)                  \
    {                                                                           \
        const int    c_  = CSLOT;                                               \
        const float4 bj  = BJSLOT;                                              \
        const float  sqc = SQSLOT;                                              \
        float p = a.x * bj.x + a.y * bj.y + a.z * bj.z + a.w * bj.w;            \
        const float dn = (sqi - 2.0f * wave_reduce_sum(p)) + sqc;               \
        CSAVE  = c_;                                                            \
        DNSAVE = dn;                                                            \
    }

// In-order break / strict-< argmin — BYTE-IDENTICAL text to passing R8/R11/R12/R14.
#define TRIAL_CHECK(CSAVE, DNSAVE)                                              \
    {                                                                           \
        const float z = dst_pos - (DNSAVE);                                     \
        if ((z < 0.0f) && (z + margin > 0.0f)) { chosen = (CSAVE); goto done; } \
        if ((DNSAVE) < best) { best = (DNSAVE); best_c = (CSAVE); }             \
    }

#define PROLOGUE_SLOT(CS, BJS, SQS, T)                                          \
    {                                                                           \
        int c = (int)(unrow[T] * lnf);                                          \
        c = min(c, lnm1);                                                       \
        c = __builtin_amdgcn_readfirstlane(c);                                  \
        CS  = c;                                                                \
        BJS = *reinterpret_cast<const float4*>(hd + c * BD + lane * 4);         \
        SQS = sq[c];                                                            \
    }

// Kernel 3: TWO waves per anchor — wave A scans trials 0..74, wave B 75..149.
// Each half runs the proven 3-deep grouped scan with per-trial early exit.
// Combine: A-hit > B-hit > strict-< argmin with tie -> A (first occurrence).
__global__ __launch_bounds__(256) void triplet_kernel(
    const float* __restrict__ hd, const int* __restrict__ tgt,
    const float* __restrict__ margin_p, const float* __restrict__ u_pos,
    const float* __restrict__ u_neg, const float* __restrict__ sq,
    const int* __restrict__ cnt, float* __restrict__ out)
{
    __shared__ int   s_chosen[2][2];
    __shared__ float s_best[2][2];
    __shared__ int   s_bestc[2][2];
    __shared__ int   s_aflag[2];

    const int lane = threadIdx.x & 63;
    const int w    = threadIdx.x >> 6;
    const int ancl = w >> 1;     // local anchor 0/1
    const int half = w & 1;      // 0: trials 0-74, 1: trials 75-149
    const int i    = blockIdx.x * 2 + ancl;

    if (threadIdx.x < 2) s_aflag[threadIdx.x] = 0;
    __syncthreads();

    // anchor row in registers (float4 per lane: 64*4 = 256 = D)
    const float4 a = *reinterpret_cast<const float4*>(hd + i * BD + lane * 4);
    const float sqi = sq[i];

    const int ng = *cnt;
    const int ti = tgt[i];
    const int len_pos = (ti == 0) ? ng : (BN - ng);
    const int len_neg = (ti == 0) ? (BN - ng) : ng;

    // positive index — exact integer/fp32 replication of the reference
    const bool excl = (i < len_pos);
    const int  eff  = len_pos - (excl ? 1 : 0);
    const float up  = u_pos[i];
    int u = (int)(up * (float)eff);        // fp32 multiply, trunc toward zero
    u = min(u, eff - 1);
    const int pos_idx = u + ((excl && (u >= i)) ? 1 : 0);

    // dst_pos = (sq_i - 2*dot) + sq_j  (same expression/order as all passing rounds;
    // computed redundantly in both halves -> identical bits -> consistent decisions)
    const float4 bp = *reinterpret_cast<const float4*>(hd + pos_idx * BD + lane * 4);
    float pp = a.x * bp.x + a.y * bp.y + a.z * bp.z + a.w * bp.w;
    const float dot_pos = wave_reduce_sum(pp);
    const float dst_pos = (sqi - 2.0f * dot_pos) + sq[pos_idx];

    float* orow = out + i * (3 * BD);
    if (half == 0) {   // anchor + positive rows; overlaps with the scan
        *reinterpret_cast<float4*>(orow + lane * 4) = a;
        *reinterpret_cast<float4*>(orow + BD + lane * 4) = bp;
    }

    const float margin = margin_p[0];
    const float lnf    = (float)len_neg;
    const int   lnm1   = len_neg - 1;

    int   chosen = -1;
    float best   = __builtin_inff();
    int   best_c = 0;
    const float* unrow = u_neg + i * NTRIALS + half * HALF;

    {
        // prologue: prefetch local trials 0,1,2 into slots A,B,C
        int cA, cB, cC; float4 bjA, bjB, bjC; float sqA, sqB, sqC;
        PROLOGUE_SLOT(cA, bjA, sqA, 0)
        PROLOGUE_SLOT(cB, bjB, sqB, 1)
        PROLOGUE_SLOT(cC, bjC, sqC, 2)

        // main loop: t = 0,3,...,69 — computes local trials t..t+2, prefetches t+3..t+5
        for (int t = 0; t < HALF - 3; t += 3) {
            int cs0, cs1, cs2;
            float dn0, dn1, dn2;
            TRIAL_COMPUTE_PF(cA, bjA, sqA, t + 3, cs0, dn0)
            TRIAL_COMPUTE_PF(cB, bjB, sqB, t + 4, cs1, dn1)
            TRIAL_COMPUTE_PF(cC, bjC, sqC, t + 5, cs2, dn2)
            TRIAL_CHECK(cs0, dn0)
            TRIAL_CHECK(cs1, dn1)
            TRIAL_CHECK(cs2, dn2)
            // B only: bail if A already hit (B's results are then discarded anyway)
            if (half && *(volatile int*)&s_aflag[ancl]) goto bail;
        }
        // peeled final group: local trials 72,73,74 — no prefetch
        {
            int cs0, cs1, cs2;
            float dn0, dn1, dn2;
            TRIAL_COMPUTE_NP(cA, bjA, sqA, cs0, dn0)
            TRIAL_COMPUTE_NP(cB, bjB, sqB, cs1, dn1)
            TRIAL_COMPUTE_NP(cC, bjC, sqC, cs2, dn2)
            TRIAL_CHECK(cs0, dn0)
            TRIAL_CHECK(cs1, dn1)
            TRIAL_CHECK(cs2, dn2)
        }
    }
done:
    if (half == 0 && chosen >= 0 && lane == 0) *(volatile int*)&s_aflag[ancl] = 1;
bail:
    if (lane == 0) {
        s_chosen[ancl][half] = chosen;
        s_best[ancl][half]   = best;
        s_bestc[ancl][half]  = best_c;
    }
    __syncthreads();

    if (half == 0) {
        const int chA = s_chosen[ancl][0];
        const int chB = s_chosen[ancl][1];
        int neg;
        if (chA >= 0) {
            neg = chA;                               // earliest hit: half A wins
        } else if (chB >= 0) {
            neg = chB;                               // hit only in half B
        } else {
            const float bA = s_best[ancl][0];
            const float bB = s_best[ancl][1];
            neg = (bB < bA) ? s_bestc[ancl][1]       // strict <: tie -> A (first occ.)
                            : s_bestc[ancl][0];
        }
        const float4 bn = *reinterpret_cast<const float4*>(hd + neg * BD + lane * 4);
        *reinterpret_cast<float4*>(orow + 2 * BD + lane * 4) = bn;
    }
}

extern "C" void kernel_launch(void* const* d_in, const int* in_sizes, int n_in,
                              void* d_out, int out_size, void* d_ws, size_t ws_size,
                              hipStream_t stream) {
    const float* hd     = (const float*)d_in[0];
    const int*   tgt    = (const int*)d_in[1];
    const float* margin = (const float*)d_in[2];
    const float* u_pos  = (const float*)d_in[3];
    const float* u_neg  = (const float*)d_in[4];
    float* out = (float*)d_out;

    float* sq  = (float*)d_ws;
    int*   cnt = (int*)((char*)d_ws + BN * sizeof(float));

    count_genuine_kernel<<<1, 1024, 0, stream>>>(tgt, cnt);
    sqnorm_kernel<<<BN / 4, 256, 0, stream>>>(hd, sq);
    triplet_kernel<<<BN / 2, 256, 0, stream>>>(hd, tgt, margin, u_pos, u_neg, sq, cnt, out);
}